// Round 9
// baseline (225.750 us; speedup 1.0000x reference)
//
#include <hip/hip_runtime.h>
#include <math.h>

#define B_N    8192
#define D_DIM  192
#define C_CLS  1024
#define MARGIN 0.2f
#define EPS_T  1e-6f

#define TI     128
#define TJ     128
#define JSPLIT 8
#define JLEN   (B_N / JSPLIT)   // 1024
#define NT     (JLEN / TJ)      // 8 tiles per block
#define RBY    384              // bytes per ebf row (192 bf16)

typedef short v8s  __attribute__((ext_vector_type(8)));
typedef float v16f __attribute__((ext_vector_type(16)));

__device__ __forceinline__ unsigned fkey(float f) {
  unsigned u = __float_as_uint(f);
  return (u & 0x80000000u) ? ~u : (u | 0x80000000u);
}

__device__ __forceinline__ unsigned short to_bf(float x) {
  unsigned u = __float_as_uint(x);
  u += 0x7fffu + ((u >> 16) & 1u);
  return (unsigned short)(u >> 16);
}

// ---------------- prep: cvt fp32->bf16, sq = ||e||^2, init ws ----------------
__global__ __launch_bounds__(256) void prep_kernel(
    const float* __restrict__ e, unsigned short* __restrict__ ebf,
    float* __restrict__ sq,
    unsigned long long* __restrict__ posw, unsigned long long* __restrict__ negw,
    float* __restrict__ accum, unsigned* __restrict__ donecnt) {
  int w = threadIdx.x >> 6, lane = threadIdx.x & 63;
  int row = blockIdx.x * 4 + w;
  const float* p = e + (size_t)row * D_DIM;
  float v0 = p[lane], v1 = p[lane + 64], v2 = p[lane + 128];
  unsigned short* q = ebf + (size_t)row * D_DIM;
  q[lane] = to_bf(v0); q[lane + 64] = to_bf(v1); q[lane + 128] = to_bf(v2);
  float s = v0 * v0 + v1 * v1 + v2 * v2;
  #pragma unroll
  for (int off = 32; off; off >>= 1) s += __shfl_xor(s, off);
  if (lane == 0) sq[row] = s;
  int b = blockIdx.x;
  if (b < 32)       posw[b * 256 + threadIdx.x] = 0ULL;
  else if (b < 64)  negw[(b - 32) * 256 + threadIdx.x] = ~0ULL;
  else if (b == 64 && threadIdx.x < 4) ((unsigned*)accum)[threadIdx.x] = 0u;
  else if (b == 65 && threadIdx.x < 64) donecnt[threadIdx.x] = 0u;
}

// ---------------- hard mining: NO tile staging (ebf is 3 MB -> L2-resident) ----------------
// 256 thr = 4 waves: wj = w&1 (j 64-band), wi = w>>1 (i 64-half). R0's verified
// wave->tile mapping and C-decode. A-fragments and B-fragments are read DIRECTLY
// from global (per-lane 16B at row*384 + kc*32 + h*16): same L2 lines the old
// staging fetched, but zero LDS round-trip and ZERO barriers in the main loop.
// Tail: fused cross-entropy, then per-i-group done counters fold the old
// trip_fin kernel into the last-arriving block of each group.
__global__ __launch_bounds__(256, 2) void mine_kernel(
    const unsigned short* __restrict__ ebf, const int* __restrict__ tgt,
    const float* __restrict__ sq, const float* __restrict__ logits,
    const float* __restrict__ emb,
    unsigned long long* __restrict__ posw, unsigned long long* __restrict__ negw,
    float* __restrict__ accum, unsigned* __restrict__ donecnt,
    float* __restrict__ out) {
  __shared__ float lds_sq[JLEN];   // 4096 B
  __shared__ int   lds_tg[JLEN];   // 4096 B
  __shared__ float ce_part[4];
  __shared__ float red[8];
  __shared__ unsigned sdone;

  const int tid  = threadIdx.x;
  const int w    = tid >> 6;
  const int lane = tid & 63;
  const int n5   = lane & 31;
  const int h    = lane >> 5;
  const int wj   = w & 1;      // j band (64 rows)
  const int wi   = w >> 1;     // i half (64 cols)
  const int i0 = blockIdx.x * TI;
  const int jb = blockIdx.y * JLEN;

  // ---- prologue: hoist block's sq/tgt span to LDS (coalesced, once) ----
  *(float4*)&lds_sq[tid * 4] = *(const float4*)(sq  + jb + tid * 4);
  *(int4*)  &lds_tg[tid * 4] = *(const int4*)  (tgt + jb + tid * 4);

  const char* eb = (const char*)ebf;
  v8s bfrag[2][12];
  #pragma unroll
  for (int tb = 0; tb < 2; ++tb) {
    const char* bp = eb + (size_t)(i0 + wi * 64 + tb * 32 + n5) * RBY + h * 16;
    #pragma unroll
    for (int kc = 0; kc < 12; ++kc)
      bfrag[tb][kc] = *(const v8s*)(bp + kc * 32);
  }
  int my_t[2];
  my_t[0] = tgt[i0 + wi * 64 + n5];
  my_t[1] = tgt[i0 + wi * 64 + 32 + n5];

  __syncthreads();   // lds_sq/lds_tg ready (the ONLY pre-tail barrier)

  float    pv[2] = {-3.4e38f, -3.4e38f}, nv[2] = {3.4e38f, 3.4e38f};
  unsigned pi_[2] = {0u, 0u}, ni_[2] = {0xFFFFFFFFu, 0xFFFFFFFFu};

  #pragma unroll 1
  for (int t = 0; t < NT; ++t) {
    const int j0 = jb + t * TJ;
    const char* ar0 = eb + (size_t)(j0 + wj * 64 +  0 + n5) * RBY + h * 16;
    const char* ar1 = eb + (size_t)(j0 + wj * 64 + 32 + n5) * RBY + h * 16;

    v16f acc[2][2];
    #pragma unroll
    for (int ta = 0; ta < 2; ++ta)
      #pragma unroll
      for (int tb = 0; tb < 2; ++tb)
        #pragma unroll
        for (int r = 0; r < 16; ++r) acc[ta][tb][r] = 0.f;

    #pragma unroll
    for (int kc = 0; kc < 12; ++kc) {
      v8s afr0 = *(const v8s*)(ar0 + kc * 32);
      v8s afr1 = *(const v8s*)(ar1 + kc * 32);
      acc[0][0] = __builtin_amdgcn_mfma_f32_32x32x16_bf16(afr0, bfrag[0][kc], acc[0][0], 0, 0, 0);
      acc[0][1] = __builtin_amdgcn_mfma_f32_32x32x16_bf16(afr0, bfrag[1][kc], acc[0][1], 0, 0, 0);
      acc[1][0] = __builtin_amdgcn_mfma_f32_32x32x16_bf16(afr1, bfrag[0][kc], acc[1][0], 0, 0, 0);
      acc[1][1] = __builtin_amdgcn_mfma_f32_32x32x16_bf16(afr1, bfrag[1][kc], acc[1][1], 0, 0, 0);
    }

    // epilogue: j = wj*64 + ta*32 + 8p + 4h + q ; i = wi*64 + tb*32 + n5
    const int jt = t * TJ;
    #pragma unroll
    for (int ta = 0; ta < 2; ++ta)
      #pragma unroll
      for (int p = 0; p < 4; ++p) {
        int jb4 = wj * 64 + ta * 32 + p * 8 + h * 4;
        float4 s4 = *(const float4*)&lds_sq[jt + jb4];   // 2 uniq addrs/wave: broadcast
        int4   t4 = *(const int4*)&lds_tg[jt + jb4];
        #pragma unroll
        for (int q = 0; q < 4; ++q) {
          float sv = (q == 0) ? s4.x : (q == 1) ? s4.y : (q == 2) ? s4.z : s4.w;
          int   tv = (q == 0) ? t4.x : (q == 1) ? t4.y : (q == 2) ? t4.z : t4.w;
          unsigned jg = (unsigned)(jb + jt + jb4 + q);
          #pragma unroll
          for (int tb = 0; tb < 2; ++tb) {
            float val = fmaf(acc[ta][tb][p * 4 + q], -2.0f, sv);
            bool same = (tv == my_t[tb]);
            if (same  && val > pv[tb]) { pv[tb] = val; pi_[tb] = jg; }
            if (!same && val < nv[tb]) { nv[tb] = val; ni_[tb] = jg; }
          }
        }
      }
  }

  // ---- merge: h-partner lanes (same i col), then global packed atomics ----
  #pragma unroll
  for (int tb = 0; tb < 2; ++tb) {
    unsigned long long pk =
        ((unsigned long long)fkey(pv[tb]) << 32) | (unsigned long long)(unsigned)(~pi_[tb]);
    unsigned long long nk =
        ((unsigned long long)fkey(nv[tb]) << 32) | (unsigned long long)ni_[tb];
    unsigned long long po = __shfl_xor(pk, 32);
    unsigned long long no = __shfl_xor(nk, 32);
    pk = pk > po ? pk : po;
    nk = nk < no ? nk : no;
    if (h == 0) {
      int irow = i0 + wi * 64 + tb * 32 + n5;
      atomicMax(&posw[irow], pk);
      atomicMin(&negw[irow], nk);
    }
  }

  // ---- fused cross-entropy: this block handles 16 logits rows ----
  {
    int blin = blockIdx.y * 64 + blockIdx.x;
    float ce_acc = 0.f;
    #pragma unroll
    for (int it = 0; it < 4; ++it) {
      int row = blin * 16 + it * 4 + w;
      const float* lp = logits + (size_t)row * C_CLS;
      float4 x[4];
      #pragma unroll
      for (int u = 0; u < 4; ++u) x[u] = *(const float4*)(lp + lane * 4 + 256 * u);
      float m = -3.4e38f;
      #pragma unroll
      for (int u = 0; u < 4; ++u)
        m = fmaxf(m, fmaxf(fmaxf(x[u].x, x[u].y), fmaxf(x[u].z, x[u].w)));
      #pragma unroll
      for (int off = 32; off; off >>= 1) m = fmaxf(m, __shfl_xor(m, off));
      float s = 0.f;
      #pragma unroll
      for (int u = 0; u < 4; ++u)
        s += __expf(x[u].x - m) + __expf(x[u].y - m) +
             __expf(x[u].z - m) + __expf(x[u].w - m);
      #pragma unroll
      for (int off = 32; off; off >>= 1) s += __shfl_xor(s, off);
      if (lane == 0) ce_acc += m + __logf(s) - lp[tgt[row]];
    }
    if (lane == 0) ce_part[w] = ce_acc;
  }
  __syncthreads();   // also drains this block's mining atomics (vmcnt 0 at barrier)
  if (tid == 0)
    atomicAdd(&accum[0], ce_part[0] + ce_part[1] + ce_part[2] + ce_part[3]);
  __threadfence();

  // ---- fused trip_fin: last block of this i-group computes its 128 triplet rows ----
  if (tid == 0) sdone = atomicAdd(&donecnt[blockIdx.x], 1u);
  __syncthreads();
  if (sdone == (unsigned)(JSPLIT - 1)) {
    float lsum = 0.f, lcnt = 0.f;
    #pragma unroll 1
    for (int r = w; r < TI; r += 4) {     // 4 waves x 32 rows
      int i = i0 + r;
      unsigned long long pp = 0ULL, np = 0ULL;
      if (lane == 0) {                    // device-coherent atomic reads
        pp = atomicOr(&posw[i], 0ULL);
        np = atomicOr(&negw[i], 0ULL);
      }
      pp = __shfl(pp, 0); np = __shfl(np, 0);
      unsigned pidx = ~(unsigned)pp;
      unsigned nidx = (unsigned)np;
      float res = 0.f, c = 0.f;
      if (pp != 0ULL && np != ~0ULL && pidx != (unsigned)i) {
        const float* pa = emb + (size_t)i * D_DIM;
        const float* pb = emb + (size_t)pidx * D_DIM;
        const float* pc = emb + (size_t)nidx * D_DIM;
        float dap = 0.f, dan = 0.f;
        #pragma unroll
        for (int u = 0; u < 3; ++u) {
          int k = lane + 64 * u;
          float av = pa[k];
          float d1 = av - pb[k] + EPS_T;
          float d2 = av - pc[k] + EPS_T;
          dap += d1 * d1;
          dan += d2 * d2;
        }
        #pragma unroll
        for (int off = 32; off; off >>= 1) {
          dap += __shfl_xor(dap, off);
          dan += __shfl_xor(dan, off);
        }
        res = fmaxf(sqrtf(dap) - sqrtf(dan) + MARGIN, 0.f);
        c = 1.f;
      }
      if (lane == 0) { lsum += res; lcnt += c; }
    }
    if (lane == 0) { red[w] = lsum; red[4 + w] = lcnt; }
    __syncthreads();
    if (tid == 0) {
      float a = red[0] + red[1] + red[2] + red[3];
      float b = red[4] + red[5] + red[6] + red[7];
      atomicAdd(&accum[1], a);
      atomicAdd(&accum[2], b);
      __threadfence();
      unsigned old = atomicAdd((unsigned*)&accum[3], 1u);
      if (old == 63u) {                   // last group-finisher: finalize
        __threadfence();
        float cls = atomicAdd(&accum[0], 0.f);   // coherent reads via atomics
        float ts  = atomicAdd(&accum[1], 0.f);
        float tc  = atomicAdd(&accum[2], 0.f);
        float trip = (tc > 0.f) ? ts / fmaxf(tc, 1.f) : 0.f;
        out[0] = cls / (float)B_N + trip;
      }
    }
  }
}

extern "C" void kernel_launch(void* const* d_in, const int* in_sizes, int n_in,
                              void* d_out, int out_size, void* d_ws, size_t ws_size,
                              hipStream_t stream) {
  const float* emb    = (const float*)d_in[0];
  const float* logits = (const float*)d_in[1];
  const int*   tgt    = (const int*)d_in[2];
  float* out = (float*)d_out;

  char* ws = (char*)d_ws;
  unsigned short* ebf = (unsigned short*)ws;                          // 3,145,728 B
  unsigned long long* posw = (unsigned long long*)(ws + 3145728);     // 65536 B
  unsigned long long* negw = (unsigned long long*)(ws + 3145728 + 65536);
  float* sq    = (float*)(ws + 3145728 + 131072);                     // 32768 B
  float* accum = (float*)(ws + 3145728 + 163840);                     // 16 B: cls,tsum,tcnt,counter
  unsigned* donecnt = (unsigned*)(ws + 3145728 + 163856);             // 256 B: per-i-group counters

  prep_kernel<<<2048, 256, 0, stream>>>(emb, ebf, sq, posw, negw, accum, donecnt);
  mine_kernel<<<dim3(B_N / TI, JSPLIT), 256, 0, stream>>>(
      ebf, tgt, sq, logits, emb, posw, negw, accum, donecnt, out);
}

// Round 10
// 202.152 us; speedup vs baseline: 1.1167x; 1.1167x over previous
//
#include <hip/hip_runtime.h>
#include <math.h>

#define B_N    8192
#define D_DIM  192
#define C_CLS  1024
#define MARGIN 0.2f
#define EPS_T  1e-6f

#define TI     128
#define TJ     128
#define JSPLIT 8
#define JLEN   (B_N / JSPLIT)   // 1024
#define NT     (JLEN / TJ)      // 8
#define LDB    200              // LDS row stride in bf16 (400 B: 16B-aligned, zero measured conflicts)

typedef short v8s  __attribute__((ext_vector_type(8)));
typedef float v16f __attribute__((ext_vector_type(16)));

__device__ __forceinline__ unsigned fkey(float f) {
  unsigned u = __float_as_uint(f);
  return (u & 0x80000000u) ? ~u : (u | 0x80000000u);
}

__device__ __forceinline__ unsigned short to_bf(float x) {
  unsigned u = __float_as_uint(x);
  u += 0x7fffu + ((u >> 16) & 1u);
  return (unsigned short)(u >> 16);
}

// ---------------- prep: cvt fp32->bf16, sq = ||e||^2, init ws ----------------
__global__ __launch_bounds__(256) void prep_kernel(
    const float* __restrict__ e, unsigned short* __restrict__ ebf,
    float* __restrict__ sq,
    unsigned long long* __restrict__ posw, unsigned long long* __restrict__ negw,
    float* __restrict__ accum, unsigned* __restrict__ donecnt) {
  int w = threadIdx.x >> 6, lane = threadIdx.x & 63;
  int row = blockIdx.x * 4 + w;
  const float* p = e + (size_t)row * D_DIM;
  float v0 = p[lane], v1 = p[lane + 64], v2 = p[lane + 128];
  unsigned short* q = ebf + (size_t)row * D_DIM;
  q[lane] = to_bf(v0); q[lane + 64] = to_bf(v1); q[lane + 128] = to_bf(v2);
  float s = v0 * v0 + v1 * v1 + v2 * v2;
  #pragma unroll
  for (int off = 32; off; off >>= 1) s += __shfl_xor(s, off);
  if (lane == 0) sq[row] = s;
  int b = blockIdx.x;
  if (b < 32)       posw[b * 256 + threadIdx.x] = 0ULL;
  else if (b < 64)  negw[(b - 32) * 256 + threadIdx.x] = ~0ULL;
  else if (b == 64 && threadIdx.x < 4) ((unsigned*)accum)[threadIdx.x] = 0u;
  else if (b == 65 && threadIdx.x < 64) donecnt[threadIdx.x] = 0u;
}

// ---------------- hard mining: R0's proven loop + fused CE + fused trip_fin ----------------
// 256 thr = 4 waves: wj = w&1 (j 64-band, ta in {0,1}), wi = w>>1 (i 64-half, tb in {0,1}).
// VALU-staged LDS with pad-200 rows (R0: 52 us, zero bank conflicts, no spill).
// 2 independent blocks/CU provide latency overlap. Tail: CE (as R0) then the
// last-arriving block of each i-group computes its 128 triplet rows and the
// 64th group-finisher writes out[0] (R9-verified protocol) -> 2 dispatches total.
__global__ __launch_bounds__(256, 2) void mine_kernel(
    const unsigned short* __restrict__ ebf, const int* __restrict__ tgt,
    const float* __restrict__ sq, const float* __restrict__ logits,
    const float* __restrict__ emb,
    unsigned long long* __restrict__ posw, unsigned long long* __restrict__ negw,
    float* __restrict__ accum, unsigned* __restrict__ donecnt,
    float* __restrict__ out) {
  __shared__ unsigned short lds_b[TJ * LDB];   // 51200 B
  __shared__ float lds_sq[JLEN];               // 4096 B
  __shared__ int   lds_tg[JLEN];               // 4096 B
  __shared__ float ce_part[4];
  __shared__ float red[8];
  __shared__ unsigned sdone;

  const int tid  = threadIdx.x;
  const int w    = tid >> 6;
  const int lane = tid & 63;
  const int n5   = lane & 31;
  const int h    = lane >> 5;
  const int wj   = w & 1;      // j band (64 rows)
  const int wi   = w >> 1;     // i half (64 cols)
  const int i0 = blockIdx.x * TI;
  const int jb = blockIdx.y * JLEN;

  // ---- prologue: hoist block's sq/tgt span to LDS + stage i-tile (coalesced) ----
  *(float4*)&lds_sq[tid * 4] = *(const float4*)(sq  + jb + tid * 4);
  *(int4*)  &lds_tg[tid * 4] = *(const int4*)  (tgt + jb + tid * 4);
  {
    const unsigned short* src = ebf + (size_t)i0 * D_DIM;
    #pragma unroll
    for (int t = 0; t < 12; ++t) {
      int c = t * 256 + tid;
      int row = c / 24;
      int off = c - row * 24;
      *(v8s*)&lds_b[row * LDB + off * 8] = *(const v8s*)(src + (size_t)row * D_DIM + off * 8);
    }
  }
  int my_t[2];
  my_t[0] = tgt[i0 + wi * 64 + n5];
  my_t[1] = tgt[i0 + wi * 64 + 32 + n5];

  __syncthreads();
  v8s bfrag[2][12];
  #pragma unroll
  for (int tb = 0; tb < 2; ++tb)
    #pragma unroll
    for (int kc = 0; kc < 12; ++kc)
      bfrag[tb][kc] = *(const v8s*)&lds_b[(wi * 64 + tb * 32 + n5) * LDB + kc * 16 + h * 8];

  float    pv[2] = {-3.4e38f, -3.4e38f}, nv[2] = {3.4e38f, 3.4e38f};
  unsigned pi_[2] = {0u, 0u}, ni_[2] = {0xFFFFFFFFu, 0xFFFFFFFFu};

  for (int t = 0; t < NT; ++t) {
    __syncthreads();   // all reads of lds_b done -> safe to overwrite
    #pragma unroll
    for (int u = 0; u < 12; ++u) {
      int c = u * 256 + tid;
      int row = c / 24;
      int off = c - row * 24;
      *(v8s*)&lds_b[row * LDB + off * 8] =
          *(const v8s*)(ebf + (size_t)(jb + t * TJ + row) * D_DIM + off * 8);
    }
    __syncthreads();   // j-tile landed

    v16f acc[2][2];
    #pragma unroll
    for (int ta = 0; ta < 2; ++ta)
      #pragma unroll
      for (int tb = 0; tb < 2; ++tb)
        #pragma unroll
        for (int r = 0; r < 16; ++r) acc[ta][tb][r] = 0.f;

    #pragma unroll
    for (int kc = 0; kc < 12; ++kc) {
      v8s afr0 = *(const v8s*)&lds_b[(wj * 64 +  0 + n5) * LDB + kc * 16 + h * 8];
      v8s afr1 = *(const v8s*)&lds_b[(wj * 64 + 32 + n5) * LDB + kc * 16 + h * 8];
      acc[0][0] = __builtin_amdgcn_mfma_f32_32x32x16_bf16(afr0, bfrag[0][kc], acc[0][0], 0, 0, 0);
      acc[0][1] = __builtin_amdgcn_mfma_f32_32x32x16_bf16(afr0, bfrag[1][kc], acc[0][1], 0, 0, 0);
      acc[1][0] = __builtin_amdgcn_mfma_f32_32x32x16_bf16(afr1, bfrag[0][kc], acc[1][0], 0, 0, 0);
      acc[1][1] = __builtin_amdgcn_mfma_f32_32x32x16_bf16(afr1, bfrag[1][kc], acc[1][1], 0, 0, 0);
    }

    // epilogue: j = wj*64 + ta*32 + 8p + 4h + q ; i = wi*64 + tb*32 + n5
    const int jt = t * TJ;
    #pragma unroll
    for (int ta = 0; ta < 2; ++ta)
      #pragma unroll
      for (int p = 0; p < 4; ++p) {
        int jb4 = wj * 64 + ta * 32 + p * 8 + h * 4;
        float4 s4 = *(const float4*)&lds_sq[jt + jb4];   // 2 uniq addrs/wave: broadcast
        int4   t4 = *(const int4*)&lds_tg[jt + jb4];
        #pragma unroll
        for (int q = 0; q < 4; ++q) {
          float sv = (q == 0) ? s4.x : (q == 1) ? s4.y : (q == 2) ? s4.z : s4.w;
          int   tv = (q == 0) ? t4.x : (q == 1) ? t4.y : (q == 2) ? t4.z : t4.w;
          unsigned jg = (unsigned)(jb + jt + jb4 + q);
          #pragma unroll
          for (int tb = 0; tb < 2; ++tb) {
            float val = fmaf(acc[ta][tb][p * 4 + q], -2.0f, sv);
            bool same = (tv == my_t[tb]);
            if (same  && val > pv[tb]) { pv[tb] = val; pi_[tb] = jg; }
            if (!same && val < nv[tb]) { nv[tb] = val; ni_[tb] = jg; }
          }
        }
      }
  }

  // ---- merge: h-partner lanes (same i col), then global packed atomics ----
  #pragma unroll
  for (int tb = 0; tb < 2; ++tb) {
    unsigned long long pk =
        ((unsigned long long)fkey(pv[tb]) << 32) | (unsigned long long)(unsigned)(~pi_[tb]);
    unsigned long long nk =
        ((unsigned long long)fkey(nv[tb]) << 32) | (unsigned long long)ni_[tb];
    unsigned long long po = __shfl_xor(pk, 32);
    unsigned long long no = __shfl_xor(nk, 32);
    pk = pk > po ? pk : po;
    nk = nk < no ? nk : no;
    if (h == 0) {
      int irow = i0 + wi * 64 + tb * 32 + n5;
      atomicMax(&posw[irow], pk);
      atomicMin(&negw[irow], nk);
    }
  }

  // ---- fused cross-entropy: this block handles 16 logits rows ----
  {
    int blin = blockIdx.y * 64 + blockIdx.x;
    float ce_acc = 0.f;
    #pragma unroll
    for (int it = 0; it < 4; ++it) {
      int row = blin * 16 + it * 4 + w;
      const float* lp = logits + (size_t)row * C_CLS;
      float4 x[4];
      #pragma unroll
      for (int u = 0; u < 4; ++u) x[u] = *(const float4*)(lp + lane * 4 + 256 * u);
      float m = -3.4e38f;
      #pragma unroll
      for (int u = 0; u < 4; ++u)
        m = fmaxf(m, fmaxf(fmaxf(x[u].x, x[u].y), fmaxf(x[u].z, x[u].w)));
      #pragma unroll
      for (int off = 32; off; off >>= 1) m = fmaxf(m, __shfl_xor(m, off));
      float s = 0.f;
      #pragma unroll
      for (int u = 0; u < 4; ++u)
        s += __expf(x[u].x - m) + __expf(x[u].y - m) +
             __expf(x[u].z - m) + __expf(x[u].w - m);
      #pragma unroll
      for (int off = 32; off; off >>= 1) s += __shfl_xor(s, off);
      if (lane == 0) ce_acc += m + __logf(s) - lp[tgt[row]];
    }
    if (lane == 0) ce_part[w] = ce_acc;
  }
  __syncthreads();
  if (tid == 0)
    atomicAdd(&accum[0], ce_part[0] + ce_part[1] + ce_part[2] + ce_part[3]);
  __threadfence();

  // ---- fused trip_fin: last block of this i-group computes its 128 triplet rows ----
  if (tid == 0) sdone = atomicAdd(&donecnt[blockIdx.x], 1u);
  __syncthreads();
  if (sdone == (unsigned)(JSPLIT - 1)) {
    float lsum = 0.f, lcnt = 0.f;
    #pragma unroll 1
    for (int r = w; r < TI; r += 4) {     // 4 waves x 32 rows
      int i = i0 + r;
      unsigned long long pp = 0ULL, np = 0ULL;
      if (lane == 0) {                    // device-coherent atomic reads
        pp = atomicOr(&posw[i], 0ULL);
        np = atomicOr(&negw[i], 0ULL);
      }
      pp = __shfl(pp, 0); np = __shfl(np, 0);
      unsigned pidx = ~(unsigned)pp;
      unsigned nidx = (unsigned)np;
      float res = 0.f, c = 0.f;
      if (pp != 0ULL && np != ~0ULL && pidx != (unsigned)i) {
        const float* pa = emb + (size_t)i * D_DIM;
        const float* pb = emb + (size_t)pidx * D_DIM;
        const float* pc = emb + (size_t)nidx * D_DIM;
        float dap = 0.f, dan = 0.f;
        #pragma unroll
        for (int u = 0; u < 3; ++u) {
          int k = lane + 64 * u;
          float av = pa[k];
          float d1 = av - pb[k] + EPS_T;
          float d2 = av - pc[k] + EPS_T;
          dap += d1 * d1;
          dan += d2 * d2;
        }
        #pragma unroll
        for (int off = 32; off; off >>= 1) {
          dap += __shfl_xor(dap, off);
          dan += __shfl_xor(dan, off);
        }
        res = fmaxf(sqrtf(dap) - sqrtf(dan) + MARGIN, 0.f);
        c = 1.f;
      }
      if (lane == 0) { lsum += res; lcnt += c; }
    }
    if (lane == 0) { red[w] = lsum; red[4 + w] = lcnt; }
    __syncthreads();
    if (tid == 0) {
      float a = red[0] + red[1] + red[2] + red[3];
      float b = red[4] + red[5] + red[6] + red[7];
      atomicAdd(&accum[1], a);
      atomicAdd(&accum[2], b);
      __threadfence();
      unsigned old = atomicAdd((unsigned*)&accum[3], 1u);
      if (old == 63u) {                   // last group-finisher: finalize
        __threadfence();
        float cls = atomicAdd(&accum[0], 0.f);   // coherent reads via atomics
        float ts  = atomicAdd(&accum[1], 0.f);
        float tc  = atomicAdd(&accum[2], 0.f);
        float trip = (tc > 0.f) ? ts / fmaxf(tc, 1.f) : 0.f;
        out[0] = cls / (float)B_N + trip;
      }
    }
  }
}

extern "C" void kernel_launch(void* const* d_in, const int* in_sizes, int n_in,
                              void* d_out, int out_size, void* d_ws, size_t ws_size,
                              hipStream_t stream) {
  const float* emb    = (const float*)d_in[0];
  const float* logits = (const float*)d_in[1];
  const int*   tgt    = (const int*)d_in[2];
  float* out = (float*)d_out;

  char* ws = (char*)d_ws;
  unsigned short* ebf = (unsigned short*)ws;                          // 3,145,728 B
  unsigned long long* posw = (unsigned long long*)(ws + 3145728);     // 65536 B
  unsigned long long* negw = (unsigned long long*)(ws + 3145728 + 65536);
  float* sq    = (float*)(ws + 3145728 + 131072);                     // 32768 B
  float* accum = (float*)(ws + 3145728 + 163840);                     // 16 B: cls,tsum,tcnt,counter
  unsigned* donecnt = (unsigned*)(ws + 3145728 + 163856);             // 256 B: per-i-group counters

  prep_kernel<<<2048, 256, 0, stream>>>(emb, ebf, sq, posw, negw, accum, donecnt);
  mine_kernel<<<dim3(B_N / TI, JSPLIT), 256, 0, stream>>>(
      ebf, tgt, sq, logits, emb, posw, negw, accum, donecnt, out);
}